// Round 1
// baseline (311.800 us; speedup 1.0000x reference)
//
#include <hip/hip_runtime.h>

// Problem constants
#define W 512
#define H 512
#define HW (512*512)          // 262144 = 2^18
#define NIMG 16
#define NCH 3
#define NGROUP 48             // NIMG*NCH
#define MBINS 4096            // median histogram bins over [0,1)
#define PBINS 1024            // percentile histogram bins, value = (bin-512)/256
#define MEDK ((HW-1)/2)       // 131071, 0-indexed lower-median rank
#define KW 23                 // filter width
#define KR 11                 // radius

// ---------------- s1d = row sums of 2D kernel (separable factor) ----------------
__global__ void k_prep(const float* __restrict__ kern, float* __restrict__ s1d) {
    int i = threadIdx.x;
    if (i < KW) {
        float s = 0.f;
        for (int j = 0; j < KW; ++j) s += kern[i*KW + j];
        s1d[i] = s;
    }
}

// ---------------- median histogram: bin = trunc(x*4096), x in [0,1) ----------------
__global__ __launch_bounds__(256) void k_hist(const float* __restrict__ x,
                                              unsigned int* __restrict__ hist) {
    __shared__ unsigned int h[MBINS];
    int g = blockIdx.x >> 4;        // 16 blocks per group
    int chunk = blockIdx.x & 15;    // 16384 elems per block
    for (int i = threadIdx.x; i < MBINS; i += 256) h[i] = 0u;
    __syncthreads();
    const float4* xp = (const float4*)(x + (size_t)g*HW + (size_t)chunk*16384);
    #pragma unroll
    for (int it = 0; it < 16; ++it) {
        float4 v = xp[it*256 + threadIdx.x];
        int b0 = min(MBINS-1, (int)(v.x * (float)MBINS));
        int b1 = min(MBINS-1, (int)(v.y * (float)MBINS));
        int b2 = min(MBINS-1, (int)(v.z * (float)MBINS));
        int b3 = min(MBINS-1, (int)(v.w * (float)MBINS));
        atomicAdd(&h[b0], 1u); atomicAdd(&h[b1], 1u);
        atomicAdd(&h[b2], 1u); atomicAdd(&h[b3], 1u);
    }
    __syncthreads();
    unsigned int* gh = hist + (size_t)g*MBINS;
    for (int i = threadIdx.x; i < MBINS; i += 256)
        if (h[i]) atomicAdd(&gh[i], h[i]);
}

// ---------------- median select: rank MEDK, within-bin interpolation ----------------
__global__ __launch_bounds__(256) void k_medsel(const unsigned int* __restrict__ hist,
                                                float* __restrict__ med) {
    __shared__ unsigned int csum[256];
    __shared__ unsigned int sel[2];   // [0]=owner thread, [1]=prefix count
    int g = blockIdx.x;
    const unsigned int* gh = hist + (size_t)g*MBINS;
    unsigned int local[16];
    unsigned int s = 0;
    #pragma unroll
    for (int i = 0; i < 16; ++i) { local[i] = gh[threadIdx.x*16 + i]; s += local[i]; }
    csum[threadIdx.x] = s;
    __syncthreads();
    if (threadIdx.x == 0) {
        unsigned int c = 0;
        for (int i = 0; i < 256; ++i) {
            if (c + csum[i] > (unsigned int)MEDK) { sel[0] = (unsigned int)i; sel[1] = c; break; }
            c += csum[i];
        }
    }
    __syncthreads();
    if (threadIdx.x == sel[0]) {
        unsigned int c = sel[1];
        #pragma unroll
        for (int i = 0; i < 16; ++i) {
            if (c + local[i] > (unsigned int)MEDK) {
                int bin = (int)threadIdx.x*16 + i;
                float frac = ((float)(MEDK - c) + 0.5f) / (float)local[i];
                med[g] = ((float)bin + frac) * (1.0f/(float)MBINS) + 0.2f;
                break;
            }
            c += local[i];
        }
    }
}

// ---------------- horizontal blur of filled image (zero "SAME" padding) ----------------
__global__ __launch_bounds__(256) void k_hblur(const float* __restrict__ x,
                                               const float* __restrict__ mask,
                                               const float* __restrict__ med,
                                               const float* __restrict__ s1d,
                                               float* __restrict__ tmp) {
    __shared__ float row[W + 2*KR];
    __shared__ float sk[KW];
    int g = blockIdx.x >> 9;     // group
    int r = blockIdx.x & 511;    // row
    int n = g / NCH;
    float medv = med[g];
    if (threadIdx.x < KW) sk[threadIdx.x] = s1d[threadIdx.x];
    const float* xr = x + (size_t)g*HW + (size_t)r*W;
    const float* mr = mask + (size_t)n*HW + (size_t)r*W;
    for (int i = threadIdx.x; i < W + 2*KR; i += 256) {
        int c = i - KR;
        float v = 0.f;
        if (c >= 0 && c < W) {
            float mv = mr[c];
            v = mv*xr[c] + (1.f - mv)*medv;
        }
        row[i] = v;
    }
    __syncthreads();
    float* tr = tmp + (size_t)g*HW + (size_t)r*W;
    for (int c = threadIdx.x; c < W; c += 256) {
        float acc = 0.f;
        #pragma unroll
        for (int j = 0; j < KW; ++j) acc += sk[j]*row[c + j];
        tr[c] = acc;
    }
}

// ------- vertical blur + res = filled - blur  (res -> d_out) + percentile hist -------
__global__ __launch_bounds__(256) void k_vblur(const float* __restrict__ x,
                                               const float* __restrict__ mask,
                                               const float* __restrict__ med,
                                               const float* __restrict__ s1d,
                                               const float* __restrict__ tmp,
                                               float* __restrict__ res,
                                               unsigned int* __restrict__ phist) {
    __shared__ unsigned int h[PBINS];
    __shared__ float sk[KW];
    for (int i = threadIdx.x; i < PBINS; i += 256) h[i] = 0u;
    if (threadIdx.x < KW) sk[threadIdx.x] = s1d[threadIdx.x];
    int b = blockIdx.x;
    int g = b >> 5;            // 32 blocks/group = 2 colblocks x 16 rowblocks
    int sub = b & 31;
    int cb = sub >> 4;         // 0..1
    int rb = sub & 15;         // 0..15
    int n = g / NCH;
    int col = cb*256 + (int)threadIdx.x;
    int r0 = rb*32;
    float acc[32];
    #pragma unroll
    for (int o = 0; o < 32; ++o) acc[o] = 0.f;
    const float* tg = tmp + (size_t)g*HW;
    __syncthreads();
    #pragma unroll
    for (int i = 0; i < 32 + 2*KR; ++i) {
        int r = r0 - KR + i;
        float v = 0.f;
        if (r >= 0 && r < H) v = tg[(size_t)r*W + col];
        #pragma unroll
        for (int o = 0; o < 32; ++o) {
            int k = i - o;
            if (k >= 0 && k < KW) acc[o] += sk[k]*v;
        }
    }
    float medv = med[g];
    const float* xg = x + (size_t)g*HW;
    const float* mg = mask + (size_t)n*HW;
    float* rg = res + (size_t)g*HW;
    #pragma unroll
    for (int o = 0; o < 32; ++o) {
        int r = r0 + o;
        float mv = mg[(size_t)r*W + col];
        float fv = mv*xg[(size_t)r*W + col] + (1.f - mv)*medv;
        float rv = fv - acc[o];
        rg[(size_t)r*W + col] = rv;
        int bin = (int)truncf(rv*256.f) + 512;
        bin = min(PBINS-1, max(0, bin));
        atomicAdd(&h[bin], 1u);
    }
    __syncthreads();
    unsigned int* gh = phist + (size_t)g*PBINS;
    for (int i = threadIdx.x; i < PBINS; i += 256)
        if (h[i]) atomicAdd(&gh[i], h[i]);
}

// ---------------- percentile select (exact on 1/256-quantized values) ----------------
__global__ __launch_bounds__(256) void k_pct(const unsigned int* __restrict__ phist,
                                             float* __restrict__ lohi) {
    __shared__ unsigned int hh[PBINS];
    int g = blockIdx.x;
    const unsigned int* gh = phist + (size_t)g*PBINS;
    for (int i = threadIdx.x; i < PBINS; i += 256) hh[i] = gh[i];
    __syncthreads();
    if (threadIdx.x == 0) {
        const double dl = (3.0/100.0)  * (double)(HW-1);   // 7864.29
        const double dh = (97.0/100.0) * (double)(HW-1);   // 254278.71
        long il = (long)dl; double fl = dl - (double)il;
        long ih = (long)dh; double fh = dh - (double)ih;
        long ranks[4] = {il, il+1, ih, ih+1};
        float v[4];
        unsigned long c = 0; int ri = 0;
        for (int b2 = 0; b2 < PBINS && ri < 4; ++b2) {
            c += hh[b2];
            while (ri < 4 && (long)c > ranks[ri]) {
                v[ri] = (float)(b2 - 512) * (1.0f/256.0f);
                ++ri;
            }
        }
        double lo = (double)v[0] + fl*((double)v[1] - (double)v[0]);
        double hi = (double)v[2] + fh*((double)v[3] - (double)v[2]);
        lohi[2*g]   = (float)lo;
        lohi[2*g+1] = (float)hi;
    }
}

// ---------------- final: out = (res - lo)/(hi - lo) * mask, in place over d_out ------
__global__ __launch_bounds__(256) void k_final(float* __restrict__ res,
                                               const float* __restrict__ mask,
                                               const float* __restrict__ lohi) {
    size_t idx4 = (size_t)blockIdx.x*256 + threadIdx.x;   // 3,145,728 total
    size_t base = idx4*4;
    int g = (int)(base >> 18);
    int n = g / NCH;
    float lo = lohi[2*g], hi = lohi[2*g+1];
    float inv = 1.0f/(hi - lo);
    float4 rv = *(const float4*)(res + base);
    float4 mv = *(const float4*)(mask + ((size_t)n << 18) + (base & (size_t)(HW-1)));
    float4 o;
    o.x = (rv.x - lo)*inv*mv.x;
    o.y = (rv.y - lo)*inv*mv.y;
    o.z = (rv.z - lo)*inv*mv.z;
    o.w = (rv.w - lo)*inv*mv.w;
    *(float4*)(res + base) = o;
}

extern "C" void kernel_launch(void* const* d_in, const int* in_sizes, int n_in,
                              void* d_out, int out_size, void* d_ws, size_t ws_size,
                              hipStream_t stream) {
    const float* x    = (const float*)d_in[0];   // [16,3,512,512] f32
    const float* mask = (const float*)d_in[1];   // [16,1,512,512] f32
    const float* kern = (const float*)d_in[2];   // [23,23] f32
    float* out = (float*)d_out;                  // 12,582,912 f32; also res scratch

    char* ws = (char*)d_ws;
    // Workspace layout (needs ~51.4 MB):
    //   [0, 786432)           hist_med : 48*4096 u32
    //   [786432, 983040)      hist_pct : 48*1024 u32
    //   [983040, 983232)      med      : 48 f32
    //   [983232, 983360)      s1d      : 23 f32 (padded)
    //   [983360, 983744)      lohi     : 96 f32
    //   [1<<20, 1<<20 + 50331648)  tmp : h-blur output
    unsigned int* hist_med = (unsigned int*)ws;
    unsigned int* hist_pct = (unsigned int*)(ws + 786432);
    float* med  = (float*)(ws + 983040);
    float* s1d  = (float*)(ws + 983232);
    float* lohi = (float*)(ws + 983360);
    float* tmp  = (float*)(ws + (1u<<20));

    hipMemsetAsync(d_ws, 0, 983744, stream);
    k_prep  <<<1,     32, 0, stream>>>(kern, s1d);
    k_hist  <<<768,  256, 0, stream>>>(x, hist_med);
    k_medsel<<<48,   256, 0, stream>>>(hist_med, med);
    k_hblur <<<24576,256, 0, stream>>>(x, mask, med, s1d, tmp);
    k_vblur <<<1536, 256, 0, stream>>>(x, mask, med, s1d, tmp, out, hist_pct);
    k_pct   <<<48,   256, 0, stream>>>(hist_pct, lohi);
    k_final <<<12288,256, 0, stream>>>(out, mask, lohi);
}

// Round 2
// 222.944 us; speedup vs baseline: 1.3986x; 1.3986x over previous
//
#include <hip/hip_runtime.h>

// Problem constants
#define W 512
#define H 512
#define HW (512*512)          // 262144
#define NCH 3
#define MBINS 4096            // median histogram bins over [0,1)
#define PBINS 1024            // percentile histogram bins, value = (bin-512)/256
#define MEDK ((HW-1)/2)       // 131071, 0-indexed lower-median rank
#define KW 23                 // filter width
#define KR 11                 // radius
#define RB 32                 // output rows per conv block
#define STG (RB + 2*KR)       // 54 staged rows per conv block

// ---------------- s1d = row sums of 2D kernel (separable factor) ----------------
__global__ void k_prep(const float* __restrict__ kern, float* __restrict__ s1d) {
    int i = threadIdx.x;
    if (i < KW) {
        float s = 0.f;
        for (int j = 0; j < KW; ++j) s += kern[i*KW + j];
        s1d[i] = s;
    }
}

// ---------------- median histogram: bin = trunc(x*4096), x in [0,1) ----------------
__global__ __launch_bounds__(256) void k_hist(const float* __restrict__ x,
                                              unsigned int* __restrict__ hist) {
    __shared__ unsigned int h[MBINS];
    int g = blockIdx.x >> 4;        // 16 blocks per group
    int chunk = blockIdx.x & 15;    // 16384 elems per block
    for (int i = threadIdx.x; i < MBINS; i += 256) h[i] = 0u;
    __syncthreads();
    const float4* xp = (const float4*)(x + (size_t)g*HW + (size_t)chunk*16384);
    #pragma unroll
    for (int it = 0; it < 16; ++it) {
        float4 v = xp[it*256 + threadIdx.x];
        int b0 = min(MBINS-1, (int)(v.x * (float)MBINS));
        int b1 = min(MBINS-1, (int)(v.y * (float)MBINS));
        int b2 = min(MBINS-1, (int)(v.z * (float)MBINS));
        int b3 = min(MBINS-1, (int)(v.w * (float)MBINS));
        atomicAdd(&h[b0], 1u); atomicAdd(&h[b1], 1u);
        atomicAdd(&h[b2], 1u); atomicAdd(&h[b3], 1u);
    }
    __syncthreads();
    unsigned int* gh = hist + (size_t)g*MBINS;
    for (int i = threadIdx.x; i < MBINS; i += 256)
        if (h[i]) atomicAdd(&gh[i], h[i]);
}

// ------ median select: parallel block scan + rank lookup (was serial thread-0) ------
__global__ __launch_bounds__(256) void k_medsel(const unsigned int* __restrict__ hist,
                                                float* __restrict__ med) {
    __shared__ unsigned int scan[256];
    const int g = blockIdx.x;
    const int tid = threadIdx.x;
    const unsigned int* gh = hist + (size_t)g*MBINS;
    unsigned int local[16];
    unsigned int s = 0;
    #pragma unroll
    for (int i = 0; i < 16; ++i) { local[i] = gh[tid*16 + i]; s += local[i]; }
    scan[tid] = s;
    __syncthreads();
    #pragma unroll
    for (int off = 1; off < 256; off <<= 1) {
        unsigned int t = (tid >= off) ? scan[tid - off] : 0u;
        __syncthreads();
        scan[tid] += t;
        __syncthreads();
    }
    unsigned int p = scan[tid] - s;   // exclusive prefix before this thread's 16 bins
    if (p <= (unsigned)MEDK && (unsigned)MEDK < p + s) {   // unique owner thread
        unsigned int c = p;
        #pragma unroll
        for (int i = 0; i < 16; ++i) {
            if (c + local[i] > (unsigned)MEDK) {
                int bin = tid*16 + i;
                float frac = ((float)(MEDK - c) + 0.5f) / (float)local[i];
                med[g] = ((float)bin + frac) * (1.0f/(float)MBINS) + 0.2f;
                break;
            }
            c += local[i];
        }
    }
}

// ---- fused separable conv + res + percentile hist (replaces k_hblur + k_vblur) ----
// Block: 512 threads own a 32-row x 512-col output band of one (n,c) group.
// Per staged row: fill (mask*x + (1-mask)*med) into LDS row, h-conv into a 23-deep
// register shift window (STATIC indices only -> no scratch demotion), emit one
// output row per iteration once the window is warm. Zero "SAME" padding both axes.
__global__ __launch_bounds__(512) void k_conv(const float* __restrict__ x,
                                              const float* __restrict__ mask,
                                              const float* __restrict__ med,
                                              const float* __restrict__ s1d,
                                              float* __restrict__ res,
                                              unsigned int* __restrict__ phist) {
    __shared__ float fillrow[W + 2*KR];
    __shared__ float sk[KW];
    __shared__ unsigned int h[PBINS];
    const int g  = blockIdx.x >> 4;   // 48 groups
    const int rb = blockIdx.x & 15;   // 16 row-bands
    const int r0 = rb * RB;
    const int n  = g / NCH;
    const int tid = threadIdx.x;
    for (int i = tid; i < PBINS; i += 512) h[i] = 0u;
    if (tid < KW) sk[tid] = s1d[tid];
    __syncthreads();
    const float medv = med[g];
    const float* xg = x    + (size_t)g*HW;
    const float* mg = mask + (size_t)n*HW;
    float*       rg = res  + (size_t)g*HW;
    const int col = tid;
    float hwin[KW];
    #pragma unroll
    for (int j = 0; j < KW; ++j) hwin[j] = 0.f;
    for (int i = 0; i < STG; ++i) {
        const int rr = r0 - KR + i;                 // absolute staged row
        const bool rowok = (rr >= 0) && (rr < H);
        #pragma unroll
        for (int u = 0; u < 2; ++u) {
            int idx = tid + u*512;
            if (idx < W + 2*KR) {
                int c = idx - KR;
                float v = 0.f;
                if (rowok && c >= 0 && c < W) {
                    float mv = mg[rr*W + c];
                    v = mv*xg[rr*W + c] + (1.f - mv)*medv;
                }
                fillrow[idx] = v;
            }
        }
        __syncthreads();
        // horizontal conv for this thread's column
        float hv = 0.f;
        #pragma unroll
        for (int j = 0; j < KW; ++j) hv += sk[j]*fillrow[col + j];
        // shift register window (all indices compile-time)
        #pragma unroll
        for (int j = 0; j < KW-1; ++j) hwin[j] = hwin[j+1];
        hwin[KW-1] = hv;
        if (i >= 2*KR) {
            const int r = r0 + i - 2*KR;            // output row
            float blur = 0.f;
            #pragma unroll
            for (int j = 0; j < KW; ++j) blur += sk[j]*hwin[j];
            float mv = mg[r*W + col];               // L1/L2 hot (staged 11 iters ago)
            float fv = mv*xg[r*W + col] + (1.f - mv)*medv;
            float rv = fv - blur;
            rg[r*W + col] = rv;
            int bin = (int)truncf(rv*256.f) + 512;
            bin = min(PBINS-1, max(0, bin));
            atomicAdd(&h[bin], 1u);
        }
        __syncthreads();   // protect fillrow before next stage overwrites it
    }
    unsigned int* gh = phist + (size_t)g*PBINS;
    for (int i = tid; i < PBINS; i += 512)
        if (h[i]) atomicAdd(&gh[i], h[i]);
}

// ------ percentile select: parallel scan + rank lookup (was 70us serial scan) ------
__global__ __launch_bounds__(256) void k_pct(const unsigned int* __restrict__ phist,
                                             float* __restrict__ lohi) {
    __shared__ unsigned int scan[256];
    __shared__ float vsh[4];
    const int g = blockIdx.x;
    const int tid = threadIdx.x;
    const unsigned int* gh = phist + (size_t)g*PBINS;
    unsigned int local[4];
    unsigned int s = 0;
    #pragma unroll
    for (int i = 0; i < 4; ++i) { local[i] = gh[tid*4 + i]; s += local[i]; }
    scan[tid] = s;
    __syncthreads();
    #pragma unroll
    for (int off = 1; off < 256; off <<= 1) {
        unsigned int t = (tid >= off) ? scan[tid - off] : 0u;
        __syncthreads();
        scan[tid] += t;
        __syncthreads();
    }
    unsigned int p = scan[tid] - s;   // exclusive prefix
    const double dl = (3.0/100.0)*(double)(HW-1);    // 7864.29
    const double dh = (97.0/100.0)*(double)(HW-1);   // 254278.71
    const long il = (long)dl, ih = (long)dh;
    const long ranks[4] = {il, il+1, ih, ih+1};
    #pragma unroll
    for (int ri = 0; ri < 4; ++ri) {
        long r = ranks[ri];
        if ((long)p <= r && r < (long)(p + s)) {     // owner thread for this rank
            unsigned int c = p;
            #pragma unroll
            for (int i = 0; i < 4; ++i) {
                if ((long)(c + local[i]) > r) {
                    vsh[ri] = (float)(tid*4 + i - 512) * (1.0f/256.0f);
                    break;
                }
                c += local[i];
            }
        }
    }
    __syncthreads();
    if (tid == 0) {
        double fl = dl - (double)il, fh = dh - (double)ih;
        double lo = (double)vsh[0] + fl*((double)vsh[1] - (double)vsh[0]);
        double hi = (double)vsh[2] + fh*((double)vsh[3] - (double)vsh[2]);
        lohi[2*g]   = (float)lo;
        lohi[2*g+1] = (float)hi;
    }
}

// ---------------- final: out = (res - lo)/(hi - lo) * mask, in place over d_out ------
__global__ __launch_bounds__(256) void k_final(float* __restrict__ res,
                                               const float* __restrict__ mask,
                                               const float* __restrict__ lohi) {
    size_t idx4 = (size_t)blockIdx.x*256 + threadIdx.x;   // 3,145,728 total
    size_t base = idx4*4;
    int g = (int)(base >> 18);
    int n = g / NCH;
    float lo = lohi[2*g], hi = lohi[2*g+1];
    float inv = 1.0f/(hi - lo);
    float4 rv = *(const float4*)(res + base);
    float4 mv = *(const float4*)(mask + ((size_t)n << 18) + (base & (size_t)(HW-1)));
    float4 o;
    o.x = (rv.x - lo)*inv*mv.x;
    o.y = (rv.y - lo)*inv*mv.y;
    o.z = (rv.z - lo)*inv*mv.z;
    o.w = (rv.w - lo)*inv*mv.w;
    *(float4*)(res + base) = o;
}

extern "C" void kernel_launch(void* const* d_in, const int* in_sizes, int n_in,
                              void* d_out, int out_size, void* d_ws, size_t ws_size,
                              hipStream_t stream) {
    const float* x    = (const float*)d_in[0];   // [16,3,512,512] f32
    const float* mask = (const float*)d_in[1];   // [16,1,512,512] f32
    const float* kern = (const float*)d_in[2];   // [23,23] f32
    float* out = (float*)d_out;                  // res scratch, normalized in place

    char* ws = (char*)d_ws;
    // Workspace layout (~1 MB, tmp eliminated):
    //   [0, 786432)        hist_med : 48*4096 u32
    //   [786432, 983040)   hist_pct : 48*1024 u32
    //   [983040, 983232)   med      : 48 f32
    //   [983232, 983360)   s1d      : 23 f32 (padded)
    //   [983360, 983744)   lohi     : 96 f32
    unsigned int* hist_med = (unsigned int*)ws;
    unsigned int* hist_pct = (unsigned int*)(ws + 786432);
    float* med  = (float*)(ws + 983040);
    float* s1d  = (float*)(ws + 983232);
    float* lohi = (float*)(ws + 983360);

    hipMemsetAsync(d_ws, 0, 983744, stream);
    k_prep  <<<1,     32, 0, stream>>>(kern, s1d);
    k_hist  <<<768,  256, 0, stream>>>(x, hist_med);
    k_medsel<<<48,   256, 0, stream>>>(hist_med, med);
    k_conv  <<<768,  512, 0, stream>>>(x, mask, med, s1d, out, hist_pct);
    k_pct   <<<48,   256, 0, stream>>>(hist_pct, lohi);
    k_final <<<12288,256, 0, stream>>>(out, mask, lohi);
}